// Round 1
// baseline (586.513 us; speedup 1.0000x reference)
//
#include <hip/hip_runtime.h>

#define FD 128

__device__ __forceinline__ float lrelu(float x, float s){ return x > 0.f ? x : s*x; }

// ---------------- CSR build (by dst, self-loops appended) ----------------
__global__ __launch_bounds__(256) void count_kernel(const int* __restrict__ ei,
                                                    int* __restrict__ counts, int E, int n){
  int i = blockIdx.x*256 + threadIdx.x;
  int tot = E + n;
  if (i >= tot) return;
  int d = (i < E) ? ei[E + i] : (i - E);
  atomicAdd(&counts[d], 1);
}

__global__ __launch_bounds__(1024) void scan_kernel(const int* __restrict__ counts,
                                                    int* __restrict__ offsets, int n){
  __shared__ int wsum[16];
  __shared__ int carry_s;
  int tid = threadIdx.x, lane = tid & 63, wv = tid >> 6;
  if (tid == 0) carry_s = 0;
  __syncthreads();
  for (int base = 0; base < n; base += 1024){
    int i = base + tid;
    int v = (i < n) ? counts[i] : 0;
    int incl = v;
    #pragma unroll
    for (int off = 1; off < 64; off <<= 1){
      int t = __shfl_up(incl, off);
      if (lane >= off) incl += t;
    }
    if (lane == 63) wsum[wv] = incl;
    __syncthreads();
    if (wv == 0 && lane < 16){
      int s = wsum[lane];
      #pragma unroll
      for (int off = 1; off < 16; off <<= 1){
        int t = __shfl_up(s, off);
        if (lane >= off) s += t;
      }
      wsum[lane] = s;
    }
    __syncthreads();
    int woff = (wv > 0) ? wsum[wv-1] : 0;
    int total = wsum[15];
    int carry = carry_s;
    if (i < n) offsets[i] = carry + woff + incl - v;
    __syncthreads();
    if (tid == 0) carry_s = carry + total;
    __syncthreads();
  }
  if (tid == 0) offsets[n] = carry_s;
}

__global__ __launch_bounds__(256) void fill_kernel(const int* __restrict__ ei,
                                                   const int* __restrict__ offsets,
                                                   int* __restrict__ cursor,
                                                   int* __restrict__ csr, int E, int n){
  int i = blockIdx.x*256 + threadIdx.x;
  int tot = E + n;
  if (i >= tot) return;
  int s, d;
  if (i < E){ s = ei[i]; d = ei[E + i]; } else { s = i - E; d = s; }
  int pos = offsets[d] + atomicAdd(&cursor[d], 1);
  csr[pos] = s;
}

// ---------------- GEMM (x@W) + per-node attention logits ----------------
// 256 threads: ch = tid&127, grp = tid>>7; each thread computes 2 nodes for its channel.
// W held in LDS (64KB). att logits reduced in-wave over 32-lane head groups.
__global__ __launch_bounds__(256) void gemm_att_kernel(
    const float* __restrict__ X, const float* __restrict__ W,
    const float* __restrict__ aSrc, const float* __restrict__ aDst,
    float* __restrict__ H, float* __restrict__ attS, float* __restrict__ attD, int n)
{
  __shared__ float Wl[FD*FD];
  int tid = threadIdx.x;
  int ch = tid & 127, grp = tid >> 7;
  for (int k = tid; k < FD*FD; k += 256) Wl[k] = W[k];
  float aS = aSrc[ch], aD = aDst[ch];
  __syncthreads();
  const float4* X4 = (const float4*)X;
  int base = blockIdx.x * 32;
  for (int it = 0; it < 32; it += 4){
    int n0 = base + it + grp*2;
    int n1 = n0 + 1;
    bool v0 = n0 < n, v1 = n1 < n;
    float acc0 = 0.f, acc1 = 0.f;
    size_t xb0 = (size_t)(v0 ? n0 : 0) * 32;
    size_t xb1 = (size_t)(v1 ? n1 : 0) * 32;
    #pragma unroll 8
    for (int k4 = 0; k4 < 32; ++k4){
      float4 xa = X4[xb0 + k4];
      float4 xb = X4[xb1 + k4];
      int k = k4 * 4;
      float w0 = Wl[(k+0)*FD + ch];
      float w1 = Wl[(k+1)*FD + ch];
      float w2 = Wl[(k+2)*FD + ch];
      float w3 = Wl[(k+3)*FD + ch];
      acc0 += xa.x*w0 + xa.y*w1 + xa.z*w2 + xa.w*w3;
      acc1 += xb.x*w0 + xb.y*w1 + xb.z*w2 + xb.w*w3;
    }
    if (v0) H[(size_t)n0*FD + ch] = acc0;
    if (v1) H[(size_t)n1*FD + ch] = acc1;
    float s0 = acc0*aS, d0 = acc0*aD, s1 = acc1*aS, d1 = acc1*aD;
    #pragma unroll
    for (int off = 16; off >= 1; off >>= 1){
      s0 += __shfl_xor(s0, off);
      d0 += __shfl_xor(d0, off);
      s1 += __shfl_xor(s1, off);
      d1 += __shfl_xor(d1, off);
    }
    if ((ch & 31) == 0){
      int head = ch >> 5;
      if (v0){ attS[n0*4 + head] = s0; attD[n0*4 + head] = d0; }
      if (v1){ attS[n1*4 + head] = s1; attD[n1*4 + head] = d1; }
    }
  }
}

// ---------------- per-dst softmax + aggregate (one wave per dst) ----------------
// lane l handles channels 2l, 2l+1 (head = l>>4). Pass 1: lane-parallel max.
// Pass 2: sequential over edges; coalesced float2 gather of h[src]; register accum.
// FUSE=1: apply bias+lrelu then fuse final FC (dot with wfc, wave-reduce) -> out[dst].
template<int FUSE>
__global__ __launch_bounds__(256) void agg_kernel(
    const float2* __restrict__ Hl, const float* __restrict__ attS, const float* __restrict__ attD,
    const int* __restrict__ csr, const int* __restrict__ offsets,
    const float* __restrict__ bias, const float* __restrict__ wfc, const float* __restrict__ bfc,
    float* __restrict__ out, int n)
{
  int wid = (int)((blockIdx.x * (size_t)blockDim.x + threadIdx.x) >> 6);
  int lane = threadIdx.x & 63;
  if (wid >= n) return;
  int start = offsets[wid], end = offsets[wid+1];
  int head = lane >> 4;
  float4 ad4 = ((const float4*)attD)[wid];
  float m0 = -3.4e38f, m1 = -3.4e38f, m2 = -3.4e38f, m3 = -3.4e38f;
  for (int j = start + lane; j < end; j += 64){
    int s = csr[j];
    float4 as4 = ((const float4*)attS)[s];
    m0 = fmaxf(m0, lrelu(as4.x + ad4.x, 0.2f));
    m1 = fmaxf(m1, lrelu(as4.y + ad4.y, 0.2f));
    m2 = fmaxf(m2, lrelu(as4.z + ad4.z, 0.2f));
    m3 = fmaxf(m3, lrelu(as4.w + ad4.w, 0.2f));
  }
  #pragma unroll
  for (int off = 32; off >= 1; off >>= 1){
    m0 = fmaxf(m0, __shfl_xor(m0, off));
    m1 = fmaxf(m1, __shfl_xor(m1, off));
    m2 = fmaxf(m2, __shfl_xor(m2, off));
    m3 = fmaxf(m3, __shfl_xor(m3, off));
  }
  float mh  = head == 0 ? m0    : head == 1 ? m1    : head == 2 ? m2    : m3;
  float adh = head == 0 ? ad4.x : head == 1 ? ad4.y : head == 2 ? ad4.z : ad4.w;
  float acc0 = 0.f, acc1 = 0.f, z = 0.f;
  for (int j = start; j < end; ++j){
    int s = csr[j];
    float e = lrelu(attS[s*4 + head] + adh, 0.2f);
    float p = expf(e - mh);
    z += p;
    float2 v = Hl[(size_t)s*64 + lane];
    acc0 += p * v.x;
    acc1 += p * v.y;
  }
  float inv = 1.f / (z + 1e-16f);
  float o0 = lrelu(acc0*inv + bias[2*lane],     0.01f);
  float o1 = lrelu(acc1*inv + bias[2*lane + 1], 0.01f);
  if (FUSE){
    float t = o0*wfc[2*lane] + o1*wfc[2*lane + 1];
    #pragma unroll
    for (int off = 32; off >= 1; off >>= 1) t += __shfl_xor(t, off);
    if (lane == 0) out[wid] = t + bfc[0];
  } else {
    ((float2*)out)[(size_t)wid*64 + lane] = make_float2(o0, o1);
  }
}

extern "C" void kernel_launch(void* const* d_in, const int* in_sizes, int n_in,
                              void* d_out, int out_size, void* d_ws, size_t ws_size,
                              hipStream_t stream)
{
  const float* x   = (const float*)d_in[0];
  const int*   ei  = (const int*)d_in[1];
  const float* W1  = (const float*)d_in[2];
  const float* aS1 = (const float*)d_in[3];
  const float* aD1 = (const float*)d_in[4];
  const float* b1  = (const float*)d_in[5];
  const float* W2  = (const float*)d_in[6];
  const float* aS2 = (const float*)d_in[7];
  const float* aD2 = (const float*)d_in[8];
  const float* b2  = (const float*)d_in[9];
  const float* Wfc = (const float*)d_in[10];
  const float* bfc = (const float*)d_in[11];
  float* out = (float*)d_out;

  int n = in_sizes[0] / FD;
  int E = in_sizes[1] / 2;
  int etot = E + n;

  char* p = (char*)d_ws;
  auto alloc = [&](size_t bytes)->void*{
    void* r = (void*)p;
    p += (bytes + 255) & ~(size_t)255;
    return r;
  };
  int* counts    = (int*)alloc((size_t)n * 4);
  int* cursor    = (int*)alloc((size_t)n * 4);
  int* offsets   = (int*)alloc((size_t)(n + 1) * 4);
  int* csr       = (int*)alloc((size_t)etot * 4);
  float* attS1   = (float*)alloc((size_t)n * 4 * 4);
  float* attD1   = (float*)alloc((size_t)n * 4 * 4);
  float* attS2   = (float*)alloc((size_t)n * 4 * 4);
  float* attD2   = (float*)alloc((size_t)n * 4 * 4);
  float* bufA    = (float*)alloc((size_t)n * FD * 4);
  float* bufB    = (float*)alloc((size_t)n * FD * 4);

  hipMemsetAsync(counts, 0, (size_t)n * 4, stream);
  hipMemsetAsync(cursor, 0, (size_t)n * 4, stream);

  int eb = (etot + 255) / 256;
  count_kernel<<<eb, 256, 0, stream>>>(ei, counts, E, n);
  scan_kernel<<<1, 1024, 0, stream>>>(counts, offsets, n);
  fill_kernel<<<eb, 256, 0, stream>>>(ei, offsets, cursor, csr, E, n);

  int gb = (n + 31) / 32;
  int ab = (int)(((size_t)n * 64 + 255) / 256);

  // layer 1
  gemm_att_kernel<<<gb, 256, 0, stream>>>(x, W1, aS1, aD1, bufA, attS1, attD1, n);
  agg_kernel<0><<<ab, 256, 0, stream>>>((const float2*)bufA, attS1, attD1, csr, offsets,
                                        b1, nullptr, nullptr, bufB, n);
  // layer 2 (+ fused FC)
  gemm_att_kernel<<<gb, 256, 0, stream>>>(bufB, W2, aS2, aD2, bufA, attS2, attD2, n);
  agg_kernel<1><<<ab, 256, 0, stream>>>((const float2*)bufA, attS2, attD2, csr, offsets,
                                        b2, Wfc, bfc, out, n);
}

// Round 2
// 414.958 us; speedup vs baseline: 1.4134x; 1.4134x over previous
//
#include <hip/hip_runtime.h>

#define FD 128

typedef __attribute__((ext_vector_type(8))) short bf16x8;
typedef __attribute__((ext_vector_type(4))) float f32x4;

__device__ __forceinline__ float lrelu(float x, float s){ return x > 0.f ? x : s*x; }

__device__ __forceinline__ unsigned short f2bf(float f){
  unsigned u = __builtin_bit_cast(unsigned, f);
  return (unsigned short)((u + 0x7FFFu + ((u >> 16) & 1u)) >> 16);
}
__device__ __forceinline__ float bf2f(unsigned short h){
  unsigned u = ((unsigned)h) << 16;
  return __builtin_bit_cast(float, u);
}

// ---------------- CSR build (by dst, self-loops appended) ----------------
__global__ __launch_bounds__(256) void count_kernel(const int* __restrict__ ei,
                                                    int* __restrict__ counts, int E, int n){
  int i = blockIdx.x*256 + threadIdx.x;
  int tot = E + n;
  if (i >= tot) return;
  int d = (i < E) ? ei[E + i] : (i - E);
  atomicAdd(&counts[d], 1);
}

__global__ __launch_bounds__(1024) void scan_kernel(const int* __restrict__ counts,
                                                    int* __restrict__ offsets, int n){
  __shared__ int wsum[16];
  __shared__ int carry_s;
  int tid = threadIdx.x, lane = tid & 63, wv = tid >> 6;
  if (tid == 0) carry_s = 0;
  __syncthreads();
  for (int base = 0; base < n; base += 4096){
    int idx = base + tid*4;
    int v0=0,v1=0,v2=0,v3=0;
    if (idx + 3 < n){
      int4 t = *(const int4*)(counts + idx);
      v0=t.x; v1=t.y; v2=t.z; v3=t.w;
    } else {
      if (idx   < n) v0 = counts[idx];
      if (idx+1 < n) v1 = counts[idx+1];
      if (idx+2 < n) v2 = counts[idx+2];
      if (idx+3 < n) v3 = counts[idx+3];
    }
    int p0=v0, p1=p0+v1, p2=p1+v2, p3=p2+v3;
    int incl = p3;
    #pragma unroll
    for (int off = 1; off < 64; off <<= 1){
      int t = __shfl_up(incl, off);
      if (lane >= off) incl += t;
    }
    if (lane == 63) wsum[wv] = incl;
    __syncthreads();
    if (wv == 0 && lane < 16){
      int s = wsum[lane];
      #pragma unroll
      for (int off = 1; off < 16; off <<= 1){
        int t = __shfl_up(s, off);
        if (lane >= off) s += t;
      }
      wsum[lane] = s;
    }
    __syncthreads();
    int woff = (wv > 0) ? wsum[wv-1] : 0;
    int carry = carry_s;
    int off0 = carry + woff + incl - p3;
    if (idx   < n) offsets[idx]   = off0;
    if (idx+1 < n) offsets[idx+1] = off0 + p0;
    if (idx+2 < n) offsets[idx+2] = off0 + p1;
    if (idx+3 < n) offsets[idx+3] = off0 + p2;
    __syncthreads();
    if (tid == 0) carry_s = carry + wsum[15];
    __syncthreads();
  }
  if (tid == 0) offsets[n] = carry_s;
}

__global__ __launch_bounds__(256) void fill_kernel(const int* __restrict__ ei,
                                                   const int* __restrict__ offsets,
                                                   int* __restrict__ cursor,
                                                   int* __restrict__ csr, int E, int n){
  int i = blockIdx.x*256 + threadIdx.x;
  int tot = E + n;
  if (i >= tot) return;
  int s, d;
  if (i < E){ s = ei[i]; d = ei[E + i]; } else { s = i - E; d = s; }
  int pos = offsets[d] + atomicAdd(&cursor[d], 1);
  csr[pos] = s;
}

// ---------------- W prep: transpose + bf16 hi/lo split ----------------
// WT[c][k] = W[k][c], stored row-major [128][128] bf16, hi and lo parts.
__global__ __launch_bounds__(256) void wprep_kernel(const float* __restrict__ W1,
                                                    const float* __restrict__ W2,
                                                    unsigned short* __restrict__ WT1h,
                                                    unsigned short* __restrict__ WT1l,
                                                    unsigned short* __restrict__ WT2h,
                                                    unsigned short* __restrict__ WT2l){
  int id = blockIdx.x*256 + threadIdx.x;  // 0..32767
  const float* W = (id < 16384) ? W1 : W2;
  unsigned short* Th = (id < 16384) ? WT1h : WT2h;
  unsigned short* Tl = (id < 16384) ? WT1l : WT2l;
  int idx = id & 16383;
  int k = idx >> 7, c = idx & 127;
  float v = W[idx];
  unsigned short h = f2bf(v);
  unsigned short l = f2bf(v - bf2f(h));
  Th[c*FD + k] = h;
  Tl[c*FD + k] = l;
}

// ---------------- MFMA GEMM: H = X @ W  (bf16 split: 3 products) ----------------
// Block 256 = 4 waves; each wave computes 16 rows x 128 cols.
// A fragment: lane(g=lane>>4, r=lane&15) holds X[rbase+r][kc*32+g*8 .. +7].
// B fragment: lane holds WT[ct*16+r][kc*32+g*8 .. +7]  (WT row-major [N][K]).
// C/D: row = rbase + g*4 + j, col = ct*16 + r.
template<int SPLITIN>
__global__ __launch_bounds__(256) void gemm_mfma_kernel(
    const float* __restrict__ Xf,
    const unsigned short* __restrict__ Xh, const unsigned short* __restrict__ Xl,
    const unsigned short* __restrict__ WTh, const unsigned short* __restrict__ WTl,
    float* __restrict__ H, int n)
{
  int tid = threadIdx.x;
  int wv = tid >> 6, lane = tid & 63;
  int g = lane >> 4, r = lane & 15;
  int rbase = blockIdx.x*64 + wv*16;
  int arow = rbase + r; if (arow >= n) arow = n - 1;

  bf16x8 Ah[4], Al[4];
  if (SPLITIN){
    const bf16x8* ph = (const bf16x8*)(Xh + (size_t)arow*FD);
    const bf16x8* pl = (const bf16x8*)(Xl + (size_t)arow*FD);
    #pragma unroll
    for (int kc = 0; kc < 4; ++kc){ Ah[kc] = ph[kc*4 + g]; Al[kc] = pl[kc*4 + g]; }
  } else {
    const float4* px = (const float4*)(Xf + (size_t)arow*FD);
    #pragma unroll
    for (int kc = 0; kc < 4; ++kc){
      float4 x0 = px[(kc*4 + g)*2];
      float4 x1 = px[(kc*4 + g)*2 + 1];
      float xs[8] = {x0.x,x0.y,x0.z,x0.w,x1.x,x1.y,x1.z,x1.w};
      #pragma unroll
      for (int t = 0; t < 8; ++t){
        unsigned short hh = f2bf(xs[t]);
        Ah[kc][t] = (short)hh;
        Al[kc][t] = (short)f2bf(xs[t] - bf2f(hh));
      }
    }
  }

  f32x4 acc[8];
  #pragma unroll
  for (int ct = 0; ct < 8; ++ct) acc[ct] = (f32x4){0.f,0.f,0.f,0.f};

  #pragma unroll
  for (int ct = 0; ct < 8; ++ct){
    int wrow = ct*16 + r;
    const bf16x8* bh = (const bf16x8*)(WTh + wrow*FD);
    const bf16x8* bl = (const bf16x8*)(WTl + wrow*FD);
    #pragma unroll
    for (int kc = 0; kc < 4; ++kc){
      bf16x8 Bh = bh[kc*4 + g];
      bf16x8 Bl = bl[kc*4 + g];
      acc[ct] = __builtin_amdgcn_mfma_f32_16x16x32_bf16(Ah[kc], Bh, acc[ct], 0, 0, 0);
      acc[ct] = __builtin_amdgcn_mfma_f32_16x16x32_bf16(Ah[kc], Bl, acc[ct], 0, 0, 0);
      acc[ct] = __builtin_amdgcn_mfma_f32_16x16x32_bf16(Al[kc], Bh, acc[ct], 0, 0, 0);
    }
  }

  #pragma unroll
  for (int j = 0; j < 4; ++j){
    int row = rbase + g*4 + j;
    if (row < n){
      #pragma unroll
      for (int ct = 0; ct < 8; ++ct){
        H[(size_t)row*FD + ct*16 + r] = acc[ct][j];
      }
    }
  }
}

// ---------------- per-node attention logits (one wave per node) ----------------
__global__ __launch_bounds__(256) void att_kernel(const float* __restrict__ H,
    const float* __restrict__ aS, const float* __restrict__ aD,
    float* __restrict__ attS, float* __restrict__ attD, int n)
{
  int wid = (int)((blockIdx.x*(size_t)256 + threadIdx.x) >> 6);
  int lane = threadIdx.x & 63;
  if (wid >= n) return;
  float2 h2  = ((const float2*)H)[(size_t)wid*64 + lane];
  float2 as2 = ((const float2*)aS)[lane];
  float2 ad2 = ((const float2*)aD)[lane];
  float s = h2.x*as2.x + h2.y*as2.y;
  float d = h2.x*ad2.x + h2.y*ad2.y;
  #pragma unroll
  for (int off = 8; off >= 1; off >>= 1){
    s += __shfl_xor(s, off);
    d += __shfl_xor(d, off);
  }
  if ((lane & 15) == 0){
    attS[wid*4 + (lane>>4)] = s;
    attD[wid*4 + (lane>>4)] = d;
  }
}

// ---------------- per-dst softmax + aggregate (one wave per dst) ----------------
// OUT=0: emit bf16 hi/lo (feeds next MFMA GEMM).  OUT=1: fuse final FC -> out[dst].
template<int OUT>
__global__ __launch_bounds__(256) void agg_kernel(
    const float2* __restrict__ Hl_, const float* __restrict__ attS, const float* __restrict__ attD,
    const int* __restrict__ csr, const int* __restrict__ offsets,
    const float* __restrict__ bias, const float* __restrict__ wfc, const float* __restrict__ bfc,
    unsigned short* __restrict__ oh, unsigned short* __restrict__ ol,
    float* __restrict__ out, int n)
{
  int wid = (int)((blockIdx.x * (size_t)blockDim.x + threadIdx.x) >> 6);
  int lane = threadIdx.x & 63;
  if (wid >= n) return;
  int start = offsets[wid], end = offsets[wid+1];
  int head = lane >> 4;
  float4 ad4 = ((const float4*)attD)[wid];
  float m0 = -3.4e38f, m1 = -3.4e38f, m2 = -3.4e38f, m3 = -3.4e38f;
  for (int j = start + lane; j < end; j += 64){
    int s = csr[j];
    float4 as4 = ((const float4*)attS)[s];
    m0 = fmaxf(m0, lrelu(as4.x + ad4.x, 0.2f));
    m1 = fmaxf(m1, lrelu(as4.y + ad4.y, 0.2f));
    m2 = fmaxf(m2, lrelu(as4.z + ad4.z, 0.2f));
    m3 = fmaxf(m3, lrelu(as4.w + ad4.w, 0.2f));
  }
  #pragma unroll
  for (int off = 32; off >= 1; off >>= 1){
    m0 = fmaxf(m0, __shfl_xor(m0, off));
    m1 = fmaxf(m1, __shfl_xor(m1, off));
    m2 = fmaxf(m2, __shfl_xor(m2, off));
    m3 = fmaxf(m3, __shfl_xor(m3, off));
  }
  float mh  = head == 0 ? m0    : head == 1 ? m1    : head == 2 ? m2    : m3;
  float adh = head == 0 ? ad4.x : head == 1 ? ad4.y : head == 2 ? ad4.z : ad4.w;
  float acc0 = 0.f, acc1 = 0.f, z = 0.f;
  for (int j = start; j < end; ++j){
    int s = csr[j];
    float e = lrelu(attS[s*4 + head] + adh, 0.2f);
    float p = expf(e - mh);
    z += p;
    float2 v = Hl_[(size_t)s*64 + lane];
    acc0 += p * v.x;
    acc1 += p * v.y;
  }
  float inv = 1.f / (z + 1e-16f);
  float o0 = lrelu(acc0*inv + bias[2*lane],     0.01f);
  float o1 = lrelu(acc1*inv + bias[2*lane + 1], 0.01f);
  if (OUT){
    float t = o0*wfc[2*lane] + o1*wfc[2*lane + 1];
    #pragma unroll
    for (int off = 32; off >= 1; off >>= 1) t += __shfl_xor(t, off);
    if (lane == 0) out[wid] = t + bfc[0];
  } else {
    unsigned short h0 = f2bf(o0);
    unsigned short h1 = f2bf(o1);
    unsigned short l0 = f2bf(o0 - bf2f(h0));
    unsigned short l1 = f2bf(o1 - bf2f(h1));
    ((unsigned*)oh)[(size_t)wid*64 + lane] = (unsigned)h0 | ((unsigned)h1 << 16);
    ((unsigned*)ol)[(size_t)wid*64 + lane] = (unsigned)l0 | ((unsigned)l1 << 16);
  }
}

extern "C" void kernel_launch(void* const* d_in, const int* in_sizes, int n_in,
                              void* d_out, int out_size, void* d_ws, size_t ws_size,
                              hipStream_t stream)
{
  const float* x   = (const float*)d_in[0];
  const int*   ei  = (const int*)d_in[1];
  const float* W1  = (const float*)d_in[2];
  const float* aS1 = (const float*)d_in[3];
  const float* aD1 = (const float*)d_in[4];
  const float* b1  = (const float*)d_in[5];
  const float* W2  = (const float*)d_in[6];
  const float* aS2 = (const float*)d_in[7];
  const float* aD2 = (const float*)d_in[8];
  const float* b2  = (const float*)d_in[9];
  const float* Wfc = (const float*)d_in[10];
  const float* bfc = (const float*)d_in[11];
  float* out = (float*)d_out;

  int n = in_sizes[0] / FD;
  int E = in_sizes[1] / 2;
  int etot = E + n;

  char* p = (char*)d_ws;
  auto alloc = [&](size_t bytes)->void*{
    void* r = (void*)p;
    p += (bytes + 255) & ~(size_t)255;
    return r;
  };
  int* counts    = (int*)alloc((size_t)n * 4);
  int* cursor    = (int*)alloc((size_t)n * 4);
  int* offsets   = (int*)alloc((size_t)(n + 1) * 4);
  int* csr       = (int*)alloc((size_t)etot * 4);
  float* attS1   = (float*)alloc((size_t)n * 4 * 4);
  float* attD1   = (float*)alloc((size_t)n * 4 * 4);
  float* attS2   = (float*)alloc((size_t)n * 4 * 4);
  float* attD2   = (float*)alloc((size_t)n * 4 * 4);
  unsigned short* WT1h = (unsigned short*)alloc(16384*2);
  unsigned short* WT1l = (unsigned short*)alloc(16384*2);
  unsigned short* WT2h = (unsigned short*)alloc(16384*2);
  unsigned short* WT2l = (unsigned short*)alloc(16384*2);
  float* Hbuf    = (float*)alloc((size_t)n * FD * 4);
  unsigned short* H2h = (unsigned short*)alloc((size_t)n * FD * 2);
  unsigned short* H2l = (unsigned short*)alloc((size_t)n * FD * 2);

  hipMemsetAsync(counts, 0, (size_t)n * 4, stream);
  hipMemsetAsync(cursor, 0, (size_t)n * 4, stream);

  int eb = (etot + 255) / 256;
  wprep_kernel<<<128, 256, 0, stream>>>(W1, W2, WT1h, WT1l, WT2h, WT2l);
  count_kernel<<<eb, 256, 0, stream>>>(ei, counts, E, n);
  scan_kernel<<<1, 1024, 0, stream>>>(counts, offsets, n);
  fill_kernel<<<eb, 256, 0, stream>>>(ei, offsets, cursor, csr, E, n);

  int gb = (n + 63) / 64;
  int ab = (int)(((size_t)n * 64 + 255) / 256);

  // layer 1
  gemm_mfma_kernel<0><<<gb, 256, 0, stream>>>(x, nullptr, nullptr, WT1h, WT1l, Hbuf, n);
  att_kernel<<<ab, 256, 0, stream>>>(Hbuf, aS1, aD1, attS1, attD1, n);
  agg_kernel<0><<<ab, 256, 0, stream>>>((const float2*)Hbuf, attS1, attD1, csr, offsets,
                                        b1, nullptr, nullptr, H2h, H2l, nullptr, n);
  // layer 2 (+ fused FC)
  gemm_mfma_kernel<1><<<gb, 256, 0, stream>>>(nullptr, H2h, H2l, WT2h, WT2l, Hbuf, n);
  att_kernel<<<ab, 256, 0, stream>>>(Hbuf, aS2, aD2, attS2, attD2, n);
  agg_kernel<1><<<ab, 256, 0, stream>>>((const float2*)Hbuf, attS2, attD2, csr, offsets,
                                        b2, Wfc, bfc, nullptr, nullptr, out, n);
}

// Round 3
// 325.191 us; speedup vs baseline: 1.8036x; 1.2760x over previous
//
#include <hip/hip_runtime.h>

#define FD 128
#define NEG_HUGE -3.4e38f

typedef __attribute__((ext_vector_type(8))) short bf16x8;
typedef __attribute__((ext_vector_type(4))) float f32x4;

__device__ __forceinline__ float lrelu(float x, float s){ return x > 0.f ? x : s*x; }

__device__ __forceinline__ unsigned short f2bf(float f){
  unsigned u = __builtin_bit_cast(unsigned, f);
  return (unsigned short)((u + 0x7FFFu + ((u >> 16) & 1u)) >> 16);
}
__device__ __forceinline__ float bf2f(unsigned short h){
  unsigned u = ((unsigned)h) << 16;
  return __builtin_bit_cast(float, u);
}

// ---------------- CSR build (by dst, self-loops appended) ----------------
__global__ __launch_bounds__(256) void count_kernel(const int* __restrict__ ei,
                                                    int* __restrict__ counts, int E, int n){
  int i = blockIdx.x*256 + threadIdx.x;
  int tot = E + n;
  if (i >= tot) return;
  int d = (i < E) ? ei[E + i] : (i - E);
  atomicAdd(&counts[d], 1);
}

__global__ __launch_bounds__(1024) void scan_kernel(const int* __restrict__ counts,
                                                    int* __restrict__ offsets, int n){
  __shared__ int wsum[16];
  __shared__ int carry_s;
  int tid = threadIdx.x, lane = tid & 63, wv = tid >> 6;
  if (tid == 0) carry_s = 0;
  __syncthreads();
  for (int base = 0; base < n; base += 4096){
    int idx = base + tid*4;
    int v0=0,v1=0,v2=0,v3=0;
    if (idx + 3 < n){
      int4 t = *(const int4*)(counts + idx);
      v0=t.x; v1=t.y; v2=t.z; v3=t.w;
    } else {
      if (idx   < n) v0 = counts[idx];
      if (idx+1 < n) v1 = counts[idx+1];
      if (idx+2 < n) v2 = counts[idx+2];
      if (idx+3 < n) v3 = counts[idx+3];
    }
    int p0=v0, p1=p0+v1, p2=p1+v2, p3=p2+v3;
    int incl = p3;
    #pragma unroll
    for (int off = 1; off < 64; off <<= 1){
      int t = __shfl_up(incl, off);
      if (lane >= off) incl += t;
    }
    if (lane == 63) wsum[wv] = incl;
    __syncthreads();
    if (wv == 0 && lane < 16){
      int s = wsum[lane];
      #pragma unroll
      for (int off = 1; off < 16; off <<= 1){
        int t = __shfl_up(s, off);
        if (lane >= off) s += t;
      }
      wsum[lane] = s;
    }
    __syncthreads();
    int woff = (wv > 0) ? wsum[wv-1] : 0;
    int carry = carry_s;
    int off0 = carry + woff + incl - p3;
    if (idx   < n) offsets[idx]   = off0;
    if (idx+1 < n) offsets[idx+1] = off0 + p0;
    if (idx+2 < n) offsets[idx+2] = off0 + p1;
    if (idx+3 < n) offsets[idx+3] = off0 + p2;
    __syncthreads();
    if (tid == 0) carry_s = carry + wsum[15];
    __syncthreads();
  }
  if (tid == 0) offsets[n] = carry_s;
}

// fill: consumes post-scan `counts` as cursors (atomicSub), leaves them at 0.
__global__ __launch_bounds__(256) void fill_kernel(const int* __restrict__ ei,
                                                   const int* __restrict__ offsets,
                                                   int* __restrict__ counts,
                                                   int* __restrict__ csr, int E, int n){
  int i = blockIdx.x*256 + threadIdx.x;
  int tot = E + n;
  if (i >= tot) return;
  int s, d;
  if (i < E){ s = ei[i]; d = ei[E + i]; } else { s = i - E; d = s; }
  int c = atomicSub(&counts[d], 1) - 1;
  csr[offsets[d] + c] = s;
}

// ---------------- W prep ----------------
// WT row-major [144][128] bf16 hi/lo:
//   rows   0..127 : WT[c][k] = W[k][c]
//   rows 128..135 : row 128+cc, cc<4: Wa_S[k][head cc]; cc in 4..7: Wa_D[k][head cc-4]
//                   Wa_S[k][h] = sum_{c<32} W[k][h*32+c]*aS[h*32+c]  (attS = X @ Wa_S)
//   rows 136..143 : zero padding (unused cols of the 9th 16-wide tile)
__global__ __launch_bounds__(256) void wprep_kernel(const float* __restrict__ W1,
                                                    const float* __restrict__ W2,
                                                    const float* __restrict__ aS1,
                                                    const float* __restrict__ aD1,
                                                    const float* __restrict__ aS2,
                                                    const float* __restrict__ aD2,
                                                    unsigned short* __restrict__ WT1h,
                                                    unsigned short* __restrict__ WT1l,
                                                    unsigned short* __restrict__ WT2h,
                                                    unsigned short* __restrict__ WT2l){
  int id = blockIdx.x*256 + threadIdx.x;
  if (id < 32768){
    const float* W = (id < 16384) ? W1 : W2;
    unsigned short* Th = (id < 16384) ? WT1h : WT2h;
    unsigned short* Tl = (id < 16384) ? WT1l : WT2l;
    int idx = id & 16383;
    int k = idx >> 7, c = idx & 127;
    float v = W[idx];
    unsigned short h = f2bf(v);
    Th[c*FD + k] = h;
    Tl[c*FD + k] = f2bf(v - bf2f(h));
  } else if (id < 34816){
    int id2 = id - 32768;            // 0..2047
    int layer = id2 >> 10;
    int id3 = id2 & 1023;            // k*8 + cc
    int k = id3 >> 3, cc = id3 & 7;
    const float* W  = layer ? W2 : W1;
    const float* av = (cc < 4) ? (layer ? aS2 : aS1) : (layer ? aD2 : aD1);
    unsigned short* Th = layer ? WT2h : WT1h;
    unsigned short* Tl = layer ? WT2l : WT1l;
    int h = cc & 3, base = h*32;
    float acc = 0.f;
    #pragma unroll 8
    for (int c = 0; c < 32; ++c) acc += W[k*FD + base + c] * av[base + c];
    unsigned short hh = f2bf(acc);
    Th[(128 + cc)*FD + k] = hh;
    Tl[(128 + cc)*FD + k] = f2bf(acc - bf2f(hh));
  } else if (id < 36864){
    int id2 = id - 34816;            // 0..2047: zero rows 136..143, both layers
    int layer = id2 >> 10;
    int id3 = id2 & 1023;
    int row = 136 + (id3 >> 7), k = id3 & 127;
    unsigned short* Th = layer ? WT2h : WT1h;
    unsigned short* Tl = layer ? WT2l : WT1l;
    Th[row*FD + k] = 0;
    Tl[row*FD + k] = 0;
  }
}

// ---------------- MFMA GEMM: [H | attS | attD] = X @ [W | WaS | WaD] ----------------
// bf16 hi/lo split, 3 MFMA products (drop lo*lo). 4 waves/block, 16 rows/wave.
template<int SPLITIN>
__global__ __launch_bounds__(256) void gemm_mfma_kernel(
    const float* __restrict__ Xf,
    const unsigned short* __restrict__ Xh, const unsigned short* __restrict__ Xl,
    const unsigned short* __restrict__ WTh, const unsigned short* __restrict__ WTl,
    float* __restrict__ H, float* __restrict__ attS, float* __restrict__ attD, int n)
{
  int tid = threadIdx.x;
  int wv = tid >> 6, lane = tid & 63;
  int g = lane >> 4, r = lane & 15;
  int rbase = blockIdx.x*64 + wv*16;
  int arow = rbase + r; if (arow >= n) arow = n - 1;

  bf16x8 Ah[4], Al[4];
  if (SPLITIN){
    const bf16x8* ph = (const bf16x8*)(Xh + (size_t)arow*FD);
    const bf16x8* pl = (const bf16x8*)(Xl + (size_t)arow*FD);
    #pragma unroll
    for (int kc = 0; kc < 4; ++kc){ Ah[kc] = ph[kc*4 + g]; Al[kc] = pl[kc*4 + g]; }
  } else {
    const float4* px = (const float4*)(Xf + (size_t)arow*FD);
    #pragma unroll
    for (int kc = 0; kc < 4; ++kc){
      float4 x0 = px[(kc*4 + g)*2];
      float4 x1 = px[(kc*4 + g)*2 + 1];
      float xs[8] = {x0.x,x0.y,x0.z,x0.w,x1.x,x1.y,x1.z,x1.w};
      #pragma unroll
      for (int t = 0; t < 8; ++t){
        unsigned short hh = f2bf(xs[t]);
        Ah[kc][t] = (short)hh;
        Al[kc][t] = (short)f2bf(xs[t] - bf2f(hh));
      }
    }
  }

  f32x4 acc[9];
  #pragma unroll
  for (int ct = 0; ct < 9; ++ct) acc[ct] = (f32x4){0.f,0.f,0.f,0.f};

  #pragma unroll
  for (int ct = 0; ct < 9; ++ct){
    int wrow = ct*16 + r;
    const bf16x8* bh = (const bf16x8*)(WTh + wrow*FD);
    const bf16x8* bl = (const bf16x8*)(WTl + wrow*FD);
    #pragma unroll
    for (int kc = 0; kc < 4; ++kc){
      bf16x8 Bh = bh[kc*4 + g];
      bf16x8 Bl = bl[kc*4 + g];
      acc[ct] = __builtin_amdgcn_mfma_f32_16x16x32_bf16(Ah[kc], Bh, acc[ct], 0, 0, 0);
      acc[ct] = __builtin_amdgcn_mfma_f32_16x16x32_bf16(Ah[kc], Bl, acc[ct], 0, 0, 0);
      acc[ct] = __builtin_amdgcn_mfma_f32_16x16x32_bf16(Al[kc], Bh, acc[ct], 0, 0, 0);
    }
  }

  #pragma unroll
  for (int j = 0; j < 4; ++j){
    int row = rbase + g*4 + j;
    if (row < n){
      #pragma unroll
      for (int ct = 0; ct < 8; ++ct){
        H[(size_t)row*FD + ct*16 + r] = acc[ct][j];
      }
      if (r < 4)      attS[row*4 + r]       = acc[8][j];
      else if (r < 8) attD[row*4 + (r - 4)] = acc[8][j];
    }
  }
}

// ---------------- per-dst online-softmax + aggregate (one wave per dst) ----------------
// Chunked (64 edges): lane-parallel p computation (one exp per edge), stash (s*64,p0..3)
// in per-wave LDS, then 4-way-parallel gather: group g handles edges jj=g,g+4,...;
// each group sweeps all 128 channels in 4 sub-steps (q) of its edge -> 4 independent
// load chains. Partial accs merged across groups via shfl_xor(16,32) at the end.
// OUT=0: emit bf16 hi/lo. OUT=1: fuse bias+lrelu+FC -> out[dst].
template<int OUT>
__global__ __launch_bounds__(256) void agg_kernel(
    const float2* __restrict__ Hl_, const float* __restrict__ attS, const float* __restrict__ attD,
    const int* __restrict__ csr, const int* __restrict__ offsets,
    const float* __restrict__ bias, const float* __restrict__ wfc, const float* __restrict__ bfc,
    unsigned short* __restrict__ oh, unsigned short* __restrict__ ol,
    float* __restrict__ out, int n)
{
  __shared__ float lds[4][64*8];
  int wid = (int)((blockIdx.x * (size_t)blockDim.x + threadIdx.x) >> 6);
  int lane = threadIdx.x & 63;
  if (wid >= n) return;
  int g = lane >> 4, r = lane & 15;
  float* wl = lds[threadIdx.x >> 6];
  int* wli = (int*)wl;

  int start = offsets[wid], end = offsets[wid+1];
  float4 ad4 = ((const float4*)attD)[wid];

  float m0=NEG_HUGE, m1=NEG_HUGE, m2=NEG_HUGE, m3=NEG_HUGE;
  float z0=0.f, z1=0.f, z2=0.f, z3=0.f;
  float acc[8];
  #pragma unroll
  for (int k = 0; k < 8; ++k) acc[k] = 0.f;

  for (int base2 = start; base2 < end; base2 += 64){
    int cnt = end - base2; if (cnt > 64) cnt = 64;
    float e0,e1,e2,e3; int sb = 0;
    if (lane < cnt){
      int s = csr[base2 + lane];
      sb = s << 6;
      float4 as4 = ((const float4*)attS)[s];
      e0 = lrelu(as4.x + ad4.x, 0.2f);
      e1 = lrelu(as4.y + ad4.y, 0.2f);
      e2 = lrelu(as4.z + ad4.z, 0.2f);
      e3 = lrelu(as4.w + ad4.w, 0.2f);
    } else { e0=e1=e2=e3=NEG_HUGE; }
    float c0=e0,c1=e1,c2=e2,c3=e3;
    #pragma unroll
    for (int off = 32; off >= 1; off >>= 1){
      c0=fmaxf(c0,__shfl_xor(c0,off)); c1=fmaxf(c1,__shfl_xor(c1,off));
      c2=fmaxf(c2,__shfl_xor(c2,off)); c3=fmaxf(c3,__shfl_xor(c3,off));
    }
    float nm0=fmaxf(m0,c0), nm1=fmaxf(m1,c1), nm2=fmaxf(m2,c2), nm3=fmaxf(m3,c3);
    if (base2 != start){
      float s0=__expf(m0-nm0), s1=__expf(m1-nm1), s2=__expf(m2-nm2), s3=__expf(m3-nm3);
      z0*=s0; z1*=s1; z2*=s2; z3*=s3;
      acc[0]*=s0; acc[1]*=s0; acc[2]*=s1; acc[3]*=s1;
      acc[4]*=s2; acc[5]*=s2; acc[6]*=s3; acc[7]*=s3;
    }
    m0=nm0; m1=nm1; m2=nm2; m3=nm3;
    float p0=__expf(e0-m0), p1=__expf(e1-m1), p2=__expf(e2-m2), p3=__expf(e3-m3);
    z0+=p0; z1+=p1; z2+=p2; z3+=p3;
    wli[lane*8]  = sb;
    wl[lane*8+4] = p0; wl[lane*8+5] = p1; wl[lane*8+6] = p2; wl[lane*8+7] = p3;
    asm volatile("s_waitcnt lgkmcnt(0)" ::: "memory");
    __builtin_amdgcn_sched_barrier(0);
    for (int jj = g; jj < cnt; jj += 4){
      int sbj = wli[jj*8];
      float4 pj = *(const float4*)&wl[jj*8+4];
      float2 v0 = Hl_[(unsigned)(sbj      + r)];
      float2 v1 = Hl_[(unsigned)(sbj + 16 + r)];
      float2 v2 = Hl_[(unsigned)(sbj + 32 + r)];
      float2 v3 = Hl_[(unsigned)(sbj + 48 + r)];
      acc[0] += pj.x*v0.x; acc[1] += pj.x*v0.y;
      acc[2] += pj.y*v1.x; acc[3] += pj.y*v1.y;
      acc[4] += pj.z*v2.x; acc[5] += pj.z*v2.y;
      acc[6] += pj.w*v3.x; acc[7] += pj.w*v3.y;
    }
    __builtin_amdgcn_sched_barrier(0);
  }

  #pragma unroll
  for (int off = 32; off >= 1; off >>= 1){
    z0+=__shfl_xor(z0,off); z1+=__shfl_xor(z1,off);
    z2+=__shfl_xor(z2,off); z3+=__shfl_xor(z3,off);
  }
  #pragma unroll
  for (int k = 0; k < 8; ++k){
    acc[k] += __shfl_xor(acc[k], 16);
    acc[k] += __shfl_xor(acc[k], 32);
  }
  float o0 = g==0?acc[0]:g==1?acc[2]:g==2?acc[4]:acc[6];
  float o1 = g==0?acc[1]:g==1?acc[3]:g==2?acc[5]:acc[7];
  float zz = g==0?z0 :g==1?z1 :g==2?z2 :z3;
  float inv = 1.f / (zz + 1e-16f);
  float2 b2v = ((const float2*)bias)[lane];
  o0 = lrelu(o0*inv + b2v.x, 0.01f);
  o1 = lrelu(o1*inv + b2v.y, 0.01f);
  if (OUT){
    float2 w2v = ((const float2*)wfc)[lane];
    float t = o0*w2v.x + o1*w2v.y;
    #pragma unroll
    for (int off = 32; off >= 1; off >>= 1) t += __shfl_xor(t, off);
    if (lane == 0) out[wid] = t + bfc[0];
  } else {
    unsigned short h0 = f2bf(o0);
    unsigned short h1 = f2bf(o1);
    unsigned short l0 = f2bf(o0 - bf2f(h0));
    unsigned short l1 = f2bf(o1 - bf2f(h1));
    ((unsigned*)oh)[(size_t)wid*64 + lane] = (unsigned)h0 | ((unsigned)h1 << 16);
    ((unsigned*)ol)[(size_t)wid*64 + lane] = (unsigned)l0 | ((unsigned)l1 << 16);
  }
}

extern "C" void kernel_launch(void* const* d_in, const int* in_sizes, int n_in,
                              void* d_out, int out_size, void* d_ws, size_t ws_size,
                              hipStream_t stream)
{
  const float* x   = (const float*)d_in[0];
  const int*   ei  = (const int*)d_in[1];
  const float* W1  = (const float*)d_in[2];
  const float* aS1 = (const float*)d_in[3];
  const float* aD1 = (const float*)d_in[4];
  const float* b1  = (const float*)d_in[5];
  const float* W2  = (const float*)d_in[6];
  const float* aS2 = (const float*)d_in[7];
  const float* aD2 = (const float*)d_in[8];
  const float* b2  = (const float*)d_in[9];
  const float* Wfc = (const float*)d_in[10];
  const float* bfc = (const float*)d_in[11];
  float* out = (float*)d_out;

  int n = in_sizes[0] / FD;
  int E = in_sizes[1] / 2;
  int etot = E + n;

  char* p = (char*)d_ws;
  auto alloc = [&](size_t bytes)->void*{
    void* r = (void*)p;
    p += (bytes + 255) & ~(size_t)255;
    return r;
  };
  int* counts    = (int*)alloc((size_t)n * 4);
  int* offsets   = (int*)alloc((size_t)(n + 1) * 4);
  int* csr       = (int*)alloc((size_t)etot * 4);
  float* attS1   = (float*)alloc((size_t)n * 4 * 4);
  float* attD1   = (float*)alloc((size_t)n * 4 * 4);
  float* attS2   = (float*)alloc((size_t)n * 4 * 4);
  float* attD2   = (float*)alloc((size_t)n * 4 * 4);
  unsigned short* WT1h = (unsigned short*)alloc(144*FD*2);
  unsigned short* WT1l = (unsigned short*)alloc(144*FD*2);
  unsigned short* WT2h = (unsigned short*)alloc(144*FD*2);
  unsigned short* WT2l = (unsigned short*)alloc(144*FD*2);
  float* Hbuf    = (float*)alloc((size_t)n * FD * 4);
  unsigned short* H2h = (unsigned short*)alloc((size_t)n * FD * 2);
  unsigned short* H2l = (unsigned short*)alloc((size_t)n * FD * 2);

  hipMemsetAsync(counts, 0, (size_t)n * 4, stream);

  int eb = (etot + 255) / 256;
  wprep_kernel<<<144, 256, 0, stream>>>(W1, W2, aS1, aD1, aS2, aD2, WT1h, WT1l, WT2h, WT2l);
  count_kernel<<<eb, 256, 0, stream>>>(ei, counts, E, n);
  scan_kernel<<<1, 1024, 0, stream>>>(counts, offsets, n);
  fill_kernel<<<eb, 256, 0, stream>>>(ei, offsets, counts, csr, E, n);

  int gb = (n + 63) / 64;
  int ab = (int)(((size_t)n * 64 + 255) / 256);

  // layer 1
  gemm_mfma_kernel<0><<<gb, 256, 0, stream>>>(x, nullptr, nullptr, WT1h, WT1l,
                                              Hbuf, attS1, attD1, n);
  agg_kernel<0><<<ab, 256, 0, stream>>>((const float2*)Hbuf, attS1, attD1, csr, offsets,
                                        b1, nullptr, nullptr, H2h, H2l, nullptr, n);
  // layer 2 (+ fused FC)
  gemm_mfma_kernel<1><<<gb, 256, 0, stream>>>(nullptr, H2h, H2l, WT2h, WT2l,
                                              Hbuf, attS2, attD2, n);
  agg_kernel<1><<<ab, 256, 0, stream>>>((const float2*)Hbuf, attS2, attD2, csr, offsets,
                                        b2, Wfc, bfc, nullptr, nullptr, out, n);
}

// Round 4
// 295.366 us; speedup vs baseline: 1.9857x; 1.1010x over previous
//
#include <hip/hip_runtime.h>
#include <hip/hip_fp16.h>

#define FD 128
#define NEG_HUGE -3.4e38f

typedef __attribute__((ext_vector_type(8))) short bf16x8;
typedef __attribute__((ext_vector_type(4))) float f32x4;

__device__ __forceinline__ float lrelu(float x, float s){ return x > 0.f ? x : s*x; }

__device__ __forceinline__ unsigned short f2bf(float f){
  unsigned u = __builtin_bit_cast(unsigned, f);
  return (unsigned short)((u + 0x7FFFu + ((u >> 16) & 1u)) >> 16);
}
__device__ __forceinline__ float bf2f(unsigned short h){
  unsigned u = ((unsigned)h) << 16;
  return __builtin_bit_cast(float, u);
}

// ---------------- CSR build (by dst, self-loops appended) ----------------
__global__ __launch_bounds__(256) void count_kernel(const int* __restrict__ ei,
                                                    int* __restrict__ counts, int E, int n){
  int i = blockIdx.x*256 + threadIdx.x;
  int tot = E + n;
  if (i >= tot) return;
  int d = (i < E) ? ei[E + i] : (i - E);
  atomicAdd(&counts[d], 1);
}

__global__ __launch_bounds__(1024) void scan_kernel(const int* __restrict__ counts,
                                                    int* __restrict__ offsets, int n){
  __shared__ int wsum[16];
  __shared__ int carry_s;
  int tid = threadIdx.x, lane = tid & 63, wv = tid >> 6;
  if (tid == 0) carry_s = 0;
  __syncthreads();
  for (int base = 0; base < n; base += 4096){
    int idx = base + tid*4;
    int v0=0,v1=0,v2=0,v3=0;
    if (idx + 3 < n){
      int4 t = *(const int4*)(counts + idx);
      v0=t.x; v1=t.y; v2=t.z; v3=t.w;
    } else {
      if (idx   < n) v0 = counts[idx];
      if (idx+1 < n) v1 = counts[idx+1];
      if (idx+2 < n) v2 = counts[idx+2];
      if (idx+3 < n) v3 = counts[idx+3];
    }
    int p0=v0, p1=p0+v1, p2=p1+v2, p3=p2+v3;
    int incl = p3;
    #pragma unroll
    for (int off = 1; off < 64; off <<= 1){
      int t = __shfl_up(incl, off);
      if (lane >= off) incl += t;
    }
    if (lane == 63) wsum[wv] = incl;
    __syncthreads();
    if (wv == 0 && lane < 16){
      int s = wsum[lane];
      #pragma unroll
      for (int off = 1; off < 16; off <<= 1){
        int t = __shfl_up(s, off);
        if (lane >= off) s += t;
      }
      wsum[lane] = s;
    }
    __syncthreads();
    int woff = (wv > 0) ? wsum[wv-1] : 0;
    int carry = carry_s;
    int off0 = carry + woff + incl - p3;
    if (idx   < n) offsets[idx]   = off0;
    if (idx+1 < n) offsets[idx+1] = off0 + p0;
    if (idx+2 < n) offsets[idx+2] = off0 + p1;
    if (idx+3 < n) offsets[idx+3] = off0 + p2;
    __syncthreads();
    if (tid == 0) carry_s = carry + wsum[15];
    __syncthreads();
  }
  if (tid == 0) offsets[n] = carry_s;
}

// fill: consumes post-scan `counts` as cursors (atomicSub), leaves them at 0.
__global__ __launch_bounds__(256) void fill_kernel(const int* __restrict__ ei,
                                                   const int* __restrict__ offsets,
                                                   int* __restrict__ counts,
                                                   int* __restrict__ csr, int E, int n){
  int i = blockIdx.x*256 + threadIdx.x;
  int tot = E + n;
  if (i >= tot) return;
  int s, d;
  if (i < E){ s = ei[i]; d = ei[E + i]; } else { s = i - E; d = s; }
  int c = atomicSub(&counts[d], 1) - 1;
  csr[offsets[d] + c] = s;
}

// ---------------- W prep ----------------
// WT row-major [144][128] bf16 hi/lo. Output channel c -> row w(c)=(c&7)*16+(c>>3)
// so GEMM thread (ct,r) produces channel r*8+ct (8 consecutive channels/thread).
// rows 128..135: att projections; rows 136..143: zero.
__global__ __launch_bounds__(256) void wprep_kernel(const float* __restrict__ W1,
                                                    const float* __restrict__ W2,
                                                    const float* __restrict__ aS1,
                                                    const float* __restrict__ aD1,
                                                    const float* __restrict__ aS2,
                                                    const float* __restrict__ aD2,
                                                    unsigned short* __restrict__ WT1h,
                                                    unsigned short* __restrict__ WT1l,
                                                    unsigned short* __restrict__ WT2h,
                                                    unsigned short* __restrict__ WT2l){
  int id = blockIdx.x*256 + threadIdx.x;
  if (id < 32768){
    const float* W = (id < 16384) ? W1 : W2;
    unsigned short* Th = (id < 16384) ? WT1h : WT2h;
    unsigned short* Tl = (id < 16384) ? WT1l : WT2l;
    int idx = id & 16383;
    int k = idx >> 7, c = idx & 127;
    int w = ((c & 7) << 4) | (c >> 3);
    float v = W[idx];
    unsigned short h = f2bf(v);
    Th[w*FD + k] = h;
    Tl[w*FD + k] = f2bf(v - bf2f(h));
  } else if (id < 34816){
    int id2 = id - 32768;
    int layer = id2 >> 10;
    int id3 = id2 & 1023;
    int k = id3 >> 3, cc = id3 & 7;
    const float* W  = layer ? W2 : W1;
    const float* av = (cc < 4) ? (layer ? aS2 : aS1) : (layer ? aD2 : aD1);
    unsigned short* Th = layer ? WT2h : WT1h;
    unsigned short* Tl = layer ? WT2l : WT1l;
    int h = cc & 3, base = h*32;
    float acc = 0.f;
    #pragma unroll 8
    for (int c = 0; c < 32; ++c) acc += W[k*FD + base + c] * av[base + c];
    unsigned short hh = f2bf(acc);
    Th[(128 + cc)*FD + k] = hh;
    Tl[(128 + cc)*FD + k] = f2bf(acc - bf2f(hh));
  } else if (id < 36864){
    int id2 = id - 34816;
    int layer = id2 >> 10;
    int id3 = id2 & 1023;
    int row = 136 + (id3 >> 7), k = id3 & 127;
    unsigned short* Th = layer ? WT2h : WT1h;
    unsigned short* Tl = layer ? WT2l : WT1l;
    Th[row*FD + k] = 0;
    Tl[row*FD + k] = 0;
  }
}

// ---------------- MFMA GEMM: [H(fp16, packed) | attS | attD] ----------------
template<int SPLITIN>
__global__ __launch_bounds__(256) void gemm_mfma_kernel(
    const float* __restrict__ Xf,
    const unsigned short* __restrict__ Xh, const unsigned short* __restrict__ Xl,
    const unsigned short* __restrict__ WTh, const unsigned short* __restrict__ WTl,
    uint4* __restrict__ H16, float* __restrict__ attS, float* __restrict__ attD, int n)
{
  int tid = threadIdx.x;
  int wv = tid >> 6, lane = tid & 63;
  int g = lane >> 4, r = lane & 15;
  int rbase = blockIdx.x*64 + wv*16;
  int arow = rbase + r; if (arow >= n) arow = n - 1;

  bf16x8 Ah[4], Al[4];
  if (SPLITIN){
    const bf16x8* ph = (const bf16x8*)(Xh + (size_t)arow*FD);
    const bf16x8* pl = (const bf16x8*)(Xl + (size_t)arow*FD);
    #pragma unroll
    for (int kc = 0; kc < 4; ++kc){ Ah[kc] = ph[kc*4 + g]; Al[kc] = pl[kc*4 + g]; }
  } else {
    const float4* px = (const float4*)(Xf + (size_t)arow*FD);
    #pragma unroll
    for (int kc = 0; kc < 4; ++kc){
      float4 x0 = px[(kc*4 + g)*2];
      float4 x1 = px[(kc*4 + g)*2 + 1];
      float xs[8] = {x0.x,x0.y,x0.z,x0.w,x1.x,x1.y,x1.z,x1.w};
      #pragma unroll
      for (int t = 0; t < 8; ++t){
        unsigned short hh = f2bf(xs[t]);
        Ah[kc][t] = (short)hh;
        Al[kc][t] = (short)f2bf(xs[t] - bf2f(hh));
      }
    }
  }

  f32x4 acc[9];
  #pragma unroll
  for (int ct = 0; ct < 9; ++ct) acc[ct] = (f32x4){0.f,0.f,0.f,0.f};

  #pragma unroll
  for (int ct = 0; ct < 9; ++ct){
    int wrow = ct*16 + r;
    const bf16x8* bh = (const bf16x8*)(WTh + wrow*FD);
    const bf16x8* bl = (const bf16x8*)(WTl + wrow*FD);
    #pragma unroll
    for (int kc = 0; kc < 4; ++kc){
      bf16x8 Bh = bh[kc*4 + g];
      bf16x8 Bl = bl[kc*4 + g];
      acc[ct] = __builtin_amdgcn_mfma_f32_16x16x32_bf16(Ah[kc], Bh, acc[ct], 0, 0, 0);
      acc[ct] = __builtin_amdgcn_mfma_f32_16x16x32_bf16(Ah[kc], Bl, acc[ct], 0, 0, 0);
      acc[ct] = __builtin_amdgcn_mfma_f32_16x16x32_bf16(Al[kc], Bh, acc[ct], 0, 0, 0);
    }
  }

  #pragma unroll
  for (int j = 0; j < 4; ++j){
    int row = rbase + g*4 + j;
    if (row < n){
      __half2 p0 = __float22half2_rn(make_float2(acc[0][j], acc[1][j]));
      __half2 p1 = __float22half2_rn(make_float2(acc[2][j], acc[3][j]));
      __half2 p2 = __float22half2_rn(make_float2(acc[4][j], acc[5][j]));
      __half2 p3 = __float22half2_rn(make_float2(acc[6][j], acc[7][j]));
      uint4 pk;
      pk.x = __builtin_bit_cast(unsigned, p0);
      pk.y = __builtin_bit_cast(unsigned, p1);
      pk.z = __builtin_bit_cast(unsigned, p2);
      pk.w = __builtin_bit_cast(unsigned, p3);
      H16[(size_t)row*16 + r] = pk;
      if (r < 4)      attS[row*4 + r]       = acc[8][j];
      else if (r < 8) attD[row*4 + (r - 4)] = acc[8][j];
    }
  }
}

// ---------------- per-dst online-softmax + aggregate (one wave per dst) ----------------
// acc[0..3] hold channels 4r..4r+3   (head r<8?0:1)
// acc[4..7] hold channels 64+4r..+3  (head r<8?2:3)
template<int OUT>
__global__ __launch_bounds__(256) void agg_kernel(
    const uint2* __restrict__ H16, const float* __restrict__ attS, const float* __restrict__ attD,
    const int* __restrict__ csr, const int* __restrict__ offsets,
    const float* __restrict__ bias, const float* __restrict__ wfc, const float* __restrict__ bfc,
    unsigned short* __restrict__ oh, unsigned short* __restrict__ ol,
    float* __restrict__ out, int n)
{
  __shared__ float lds[4][64*8];
  int wid = (int)((blockIdx.x * (size_t)blockDim.x + threadIdx.x) >> 6);
  int lane = threadIdx.x & 63;
  if (wid >= n) return;
  int g = lane >> 4, r = lane & 15;
  float* wl = lds[threadIdx.x >> 6];
  int* wli = (int*)wl;

  int start = offsets[wid], end = offsets[wid+1];
  float4 ad4 = ((const float4*)attD)[wid];

  float m0=NEG_HUGE, m1=NEG_HUGE, m2=NEG_HUGE, m3=NEG_HUGE;
  float z0=0.f, z1=0.f, z2=0.f, z3=0.f;
  float acc[8];
  #pragma unroll
  for (int k = 0; k < 8; ++k) acc[k] = 0.f;

  for (int base2 = start; base2 < end; base2 += 64){
    int cnt = end - base2; if (cnt > 64) cnt = 64;
    float e0,e1,e2,e3; int sb = 0;
    if (lane < cnt){
      int s = csr[base2 + lane];
      sb = s << 5;                    // 32 uint2 per 256B row
      float4 as4 = ((const float4*)attS)[s];
      e0 = lrelu(as4.x + ad4.x, 0.2f);
      e1 = lrelu(as4.y + ad4.y, 0.2f);
      e2 = lrelu(as4.z + ad4.z, 0.2f);
      e3 = lrelu(as4.w + ad4.w, 0.2f);
    } else { e0=e1=e2=e3=NEG_HUGE; }
    float c0=e0,c1=e1,c2=e2,c3=e3;
    #pragma unroll
    for (int off = 32; off >= 1; off >>= 1){
      c0=fmaxf(c0,__shfl_xor(c0,off)); c1=fmaxf(c1,__shfl_xor(c1,off));
      c2=fmaxf(c2,__shfl_xor(c2,off)); c3=fmaxf(c3,__shfl_xor(c3,off));
    }
    float nm0=fmaxf(m0,c0), nm1=fmaxf(m1,c1), nm2=fmaxf(m2,c2), nm3=fmaxf(m3,c3);
    if (base2 != start){
      float s0=__expf(m0-nm0), s1=__expf(m1-nm1), s2=__expf(m2-nm2), s3=__expf(m3-nm3);
      z0*=s0; z1*=s1; z2*=s2; z3*=s3;
      float sa = (r < 8) ? s0 : s1;   // scale for acc[0..3]'s head
      float sc = (r < 8) ? s2 : s3;   // scale for acc[4..7]'s head
      acc[0]*=sa; acc[1]*=sa; acc[2]*=sa; acc[3]*=sa;
      acc[4]*=sc; acc[5]*=sc; acc[6]*=sc; acc[7]*=sc;
    }
    m0=nm0; m1=nm1; m2=nm2; m3=nm3;
    float p0=__expf(e0-m0), p1=__expf(e1-m1), p2=__expf(e2-m2), p3=__expf(e3-m3);
    z0+=p0; z1+=p1; z2+=p2; z3+=p3;
    wli[lane*8]  = sb;
    wl[lane*8+4] = p0; wl[lane*8+5] = p1; wl[lane*8+6] = p2; wl[lane*8+7] = p3;
    asm volatile("s_waitcnt lgkmcnt(0)" ::: "memory");
    __builtin_amdgcn_sched_barrier(0);
    for (int jj = g; jj < cnt; jj += 4){
      int sbj = wli[jj*8];
      float4 pj = *(const float4*)&wl[jj*8+4];
      uint2 u0 = H16[(unsigned)(sbj + r)];
      uint2 u1 = H16[(unsigned)(sbj + 16 + r)];
      float2 a0 = __half22float2(__builtin_bit_cast(__half2, u0.x));
      float2 a1 = __half22float2(__builtin_bit_cast(__half2, u0.y));
      float2 a2 = __half22float2(__builtin_bit_cast(__half2, u1.x));
      float2 a3 = __half22float2(__builtin_bit_cast(__half2, u1.y));
      float mA = (r < 8) ? pj.x : pj.y;
      float mB = (r < 8) ? pj.z : pj.w;
      acc[0] += mA*a0.x; acc[1] += mA*a0.y; acc[2] += mA*a1.x; acc[3] += mA*a1.y;
      acc[4] += mB*a2.x; acc[5] += mB*a2.y; acc[6] += mB*a3.x; acc[7] += mB*a3.y;
    }
    __builtin_amdgcn_sched_barrier(0);
  }

  #pragma unroll
  for (int off = 32; off >= 1; off >>= 1){
    z0+=__shfl_xor(z0,off); z1+=__shfl_xor(z1,off);
    z2+=__shfl_xor(z2,off); z3+=__shfl_xor(z3,off);
  }
  #pragma unroll
  for (int k = 0; k < 8; ++k){
    acc[k] += __shfl_xor(acc[k], 16);
    acc[k] += __shfl_xor(acc[k], 32);
  }
  // group g keeps channels ch0 = (g>>1)*64 + 4r + 2*(g&1), ch1 = ch0+1
  float o0 = g==0?acc[0]:g==1?acc[2]:g==2?acc[4]:acc[6];
  float o1 = g==0?acc[1]:g==1?acc[3]:g==2?acc[5]:acc[7];
  int ch0 = ((g>>1)<<6) + (r<<2) + ((g&1)<<1);
  float zz = (g < 2) ? ((r<8)? z0 : z1) : ((r<8)? z2 : z3);
  float inv = 1.f / (zz + 1e-16f);
  float2 b2v = ((const float2*)bias)[ch0 >> 1];
  o0 = lrelu(o0*inv + b2v.x, 0.01f);
  o1 = lrelu(o1*inv + b2v.y, 0.01f);
  if (OUT){
    float2 w2v = ((const float2*)wfc)[ch0 >> 1];
    float t = o0*w2v.x + o1*w2v.y;
    #pragma unroll
    for (int off = 32; off >= 1; off >>= 1) t += __shfl_xor(t, off);
    if (lane == 0) out[wid] = t + bfc[0];
  } else {
    unsigned short h0 = f2bf(o0);
    unsigned short h1 = f2bf(o1);
    unsigned short l0 = f2bf(o0 - bf2f(h0));
    unsigned short l1 = f2bf(o1 - bf2f(h1));
    ((unsigned*)oh)[(size_t)wid*64 + (ch0>>1)] = (unsigned)h0 | ((unsigned)h1 << 16);
    ((unsigned*)ol)[(size_t)wid*64 + (ch0>>1)] = (unsigned)l0 | ((unsigned)l1 << 16);
  }
}

extern "C" void kernel_launch(void* const* d_in, const int* in_sizes, int n_in,
                              void* d_out, int out_size, void* d_ws, size_t ws_size,
                              hipStream_t stream)
{
  const float* x   = (const float*)d_in[0];
  const int*   ei  = (const int*)d_in[1];
  const float* W1  = (const float*)d_in[2];
  const float* aS1 = (const float*)d_in[3];
  const float* aD1 = (const float*)d_in[4];
  const float* b1  = (const float*)d_in[5];
  const float* W2  = (const float*)d_in[6];
  const float* aS2 = (const float*)d_in[7];
  const float* aD2 = (const float*)d_in[8];
  const float* b2  = (const float*)d_in[9];
  const float* Wfc = (const float*)d_in[10];
  const float* bfc = (const float*)d_in[11];
  float* out = (float*)d_out;

  int n = in_sizes[0] / FD;
  int E = in_sizes[1] / 2;
  int etot = E + n;

  char* p = (char*)d_ws;
  auto alloc = [&](size_t bytes)->void*{
    void* r = (void*)p;
    p += (bytes + 255) & ~(size_t)255;
    return r;
  };
  int* counts    = (int*)alloc((size_t)n * 4);
  int* offsets   = (int*)alloc((size_t)(n + 1) * 4);
  int* csr       = (int*)alloc((size_t)etot * 4);
  float* attS1   = (float*)alloc((size_t)n * 4 * 4);
  float* attD1   = (float*)alloc((size_t)n * 4 * 4);
  float* attS2   = (float*)alloc((size_t)n * 4 * 4);
  float* attD2   = (float*)alloc((size_t)n * 4 * 4);
  unsigned short* WT1h = (unsigned short*)alloc(144*FD*2);
  unsigned short* WT1l = (unsigned short*)alloc(144*FD*2);
  unsigned short* WT2h = (unsigned short*)alloc(144*FD*2);
  unsigned short* WT2l = (unsigned short*)alloc(144*FD*2);
  uint4* H16     = (uint4*)alloc((size_t)n * FD * 2);
  unsigned short* H2h = (unsigned short*)alloc((size_t)n * FD * 2);
  unsigned short* H2l = (unsigned short*)alloc((size_t)n * FD * 2);

  hipMemsetAsync(counts, 0, (size_t)n * 4, stream);

  int eb = (etot + 255) / 256;
  wprep_kernel<<<144, 256, 0, stream>>>(W1, W2, aS1, aD1, aS2, aD2, WT1h, WT1l, WT2h, WT2l);
  count_kernel<<<eb, 256, 0, stream>>>(ei, counts, E, n);
  scan_kernel<<<1, 1024, 0, stream>>>(counts, offsets, n);
  fill_kernel<<<eb, 256, 0, stream>>>(ei, offsets, counts, csr, E, n);

  int gb = (n + 63) / 64;
  int ab = (int)(((size_t)n * 64 + 255) / 256);

  // layer 1
  gemm_mfma_kernel<0><<<gb, 256, 0, stream>>>(x, nullptr, nullptr, WT1h, WT1l,
                                              H16, attS1, attD1, n);
  agg_kernel<0><<<ab, 256, 0, stream>>>((const uint2*)H16, attS1, attD1, csr, offsets,
                                        b1, nullptr, nullptr, H2h, H2l, nullptr, n);
  // layer 2 (+ fused FC)
  gemm_mfma_kernel<1><<<gb, 256, 0, stream>>>(nullptr, H2h, H2l, WT2h, WT2l,
                                              H16, attS2, attD2, n);
  agg_kernel<1><<<ab, 256, 0, stream>>>((const uint2*)H16, attS2, attD2, csr, offsets,
                                        b2, Wfc, bfc, nullptr, nullptr, out, n);
}

// Round 5
// 276.966 us; speedup vs baseline: 2.1176x; 1.0664x over previous
//
#include <hip/hip_runtime.h>
#include <hip/hip_fp16.h>

#define FD 128

typedef __attribute__((ext_vector_type(8))) short bf16x8;
typedef __attribute__((ext_vector_type(4))) float f32x4;

__device__ __forceinline__ float lrelu(float x, float s){ return x > 0.f ? x : s*x; }

__device__ __forceinline__ unsigned short f2bf(float f){
  unsigned u = __builtin_bit_cast(unsigned, f);
  return (unsigned short)((u + 0x7FFFu + ((u >> 16) & 1u)) >> 16);
}
__device__ __forceinline__ float bf2f(unsigned short h){
  unsigned u = ((unsigned)h) << 16;
  return __builtin_bit_cast(float, u);
}

// ---------------- XCD-partitioned CSR build (by dst; self-loops via scan +1) ----------------
// Block b: xcd = b&7, chunk = b>>3. Each block scans the whole edge list slice of its
// chunk but only processes dsts in its XCD's range -> csr writes stay XCD-L2-local
// (offsets monotonic => dst range = contiguous csr slice). 8x coalesced re-read is
// far cheaper than cross-XCD line-eviction scatter.
__global__ __launch_bounds__(256) void count_part_kernel(const int* __restrict__ dst,
    int* __restrict__ counts, int E, unsigned rscale, int nchunk){
  int b = blockIdx.x;
  int xcd = b & 7, chunk = b >> 3;
  int nv = E >> 2;
  for (int v = chunk*256 + threadIdx.x; v < nv; v += nchunk*256){
    int4 d4 = ((const int4*)dst)[v];
    #pragma unroll
    for (int t = 0; t < 4; ++t){
      int d = (&d4.x)[t];
      unsigned r = (unsigned)(((unsigned long long)(unsigned)d * rscale) >> 32);
      if ((int)r == xcd) atomicAdd(&counts[d], 1);
    }
  }
  if (chunk == 0 && threadIdx.x < (E & 3)){
    int i = (E & ~3) + threadIdx.x;
    int d = dst[i];
    unsigned r = (unsigned)(((unsigned long long)(unsigned)d * rscale) >> 32);
    if ((int)r == xcd) atomicAdd(&counts[d], 1);
  }
}

__global__ __launch_bounds__(256) void fill_part_kernel(const int* __restrict__ ei,
    const int* __restrict__ offsets, int* __restrict__ counts, int* __restrict__ csr,
    int E, unsigned rscale, int nchunk){
  int b = blockIdx.x;
  int xcd = b & 7, chunk = b >> 3;
  int nv = E >> 2;
  for (int v = chunk*256 + threadIdx.x; v < nv; v += nchunk*256){
    int4 s4 = ((const int4*)ei)[v];
    int4 d4 = ((const int4*)(ei + E))[v];
    #pragma unroll
    for (int t = 0; t < 4; ++t){
      int d = (&d4.x)[t];
      unsigned r = (unsigned)(((unsigned long long)(unsigned)d * rscale) >> 32);
      if ((int)r == xcd){
        int c = atomicSub(&counts[d], 1) - 1;
        csr[offsets[d] + c] = (&s4.x)[t];
      }
    }
  }
  if (chunk == 0 && threadIdx.x < (E & 3)){
    int i = (E & ~3) + threadIdx.x;
    int d = ei[E + i];
    unsigned r = (unsigned)(((unsigned long long)(unsigned)d * rscale) >> 32);
    if ((int)r == xcd){
      int c = atomicSub(&counts[d], 1) - 1;
      csr[offsets[d] + c] = ei[i];
    }
  }
}

// self-loop of d goes in the LAST slot of d's row (slots 0..deg-1 used by fill).
__global__ __launch_bounds__(256) void selfloop_kernel(const int* __restrict__ offsets,
                                                       int* __restrict__ csr, int n){
  int d = blockIdx.x*256 + threadIdx.x;
  if (d < n) csr[offsets[d+1] - 1] = d;
}

// scan of (counts[i] + 1): +1 reserves the self-loop slot per node.
__global__ __launch_bounds__(1024) void scan_kernel(const int* __restrict__ counts,
                                                    int* __restrict__ offsets, int n){
  __shared__ int wsum[16];
  __shared__ int carry_s;
  int tid = threadIdx.x, lane = tid & 63, wv = tid >> 6;
  if (tid == 0) carry_s = 0;
  __syncthreads();
  for (int base = 0; base < n; base += 4096){
    int idx = base + tid*4;
    int v0=0,v1=0,v2=0,v3=0;
    if (idx + 3 < n){
      int4 t = *(const int4*)(counts + idx);
      v0=t.x+1; v1=t.y+1; v2=t.z+1; v3=t.w+1;
    } else {
      if (idx   < n) v0 = counts[idx]+1;
      if (idx+1 < n) v1 = counts[idx+1]+1;
      if (idx+2 < n) v2 = counts[idx+2]+1;
      if (idx+3 < n) v3 = counts[idx+3]+1;
    }
    int p0=v0, p1=p0+v1, p2=p1+v2, p3=p2+v3;
    int incl = p3;
    #pragma unroll
    for (int off = 1; off < 64; off <<= 1){
      int t = __shfl_up(incl, off);
      if (lane >= off) incl += t;
    }
    if (lane == 63) wsum[wv] = incl;
    __syncthreads();
    if (wv == 0 && lane < 16){
      int s = wsum[lane];
      #pragma unroll
      for (int off = 1; off < 16; off <<= 1){
        int t = __shfl_up(s, off);
        if (lane >= off) s += t;
      }
      wsum[lane] = s;
    }
    __syncthreads();
    int woff = (wv > 0) ? wsum[wv-1] : 0;
    int carry = carry_s;
    int off0 = carry + woff + incl - p3;
    if (idx   < n) offsets[idx]   = off0;
    if (idx+1 < n) offsets[idx+1] = off0 + p0;
    if (idx+2 < n) offsets[idx+2] = off0 + p1;
    if (idx+3 < n) offsets[idx+3] = off0 + p2;
    __syncthreads();
    if (tid == 0) carry_s = carry + wsum[15];
    __syncthreads();
  }
  if (tid == 0) offsets[n] = carry_s;
}

// ---------------- W prep ----------------
// WT row-major [144][128] bf16 hi/lo. Output channel c -> row w(c)=(c&7)*16+(c>>3)
// so GEMM thread (ct,r) produces channel r*8+ct (8 consecutive channels/thread).
// rows 128..135: att projections; rows 136..143: zero.
__global__ __launch_bounds__(256) void wprep_kernel(const float* __restrict__ W1,
                                                    const float* __restrict__ W2,
                                                    const float* __restrict__ aS1,
                                                    const float* __restrict__ aD1,
                                                    const float* __restrict__ aS2,
                                                    const float* __restrict__ aD2,
                                                    unsigned short* __restrict__ WT1h,
                                                    unsigned short* __restrict__ WT1l,
                                                    unsigned short* __restrict__ WT2h,
                                                    unsigned short* __restrict__ WT2l){
  int id = blockIdx.x*256 + threadIdx.x;
  if (id < 32768){
    const float* W = (id < 16384) ? W1 : W2;
    unsigned short* Th = (id < 16384) ? WT1h : WT2h;
    unsigned short* Tl = (id < 16384) ? WT1l : WT2l;
    int idx = id & 16383;
    int k = idx >> 7, c = idx & 127;
    int w = ((c & 7) << 4) | (c >> 3);
    float v = W[idx];
    unsigned short h = f2bf(v);
    Th[w*FD + k] = h;
    Tl[w*FD + k] = f2bf(v - bf2f(h));
  } else if (id < 34816){
    int id2 = id - 32768;
    int layer = id2 >> 10;
    int id3 = id2 & 1023;
    int k = id3 >> 3, cc = id3 & 7;
    const float* W  = layer ? W2 : W1;
    const float* av = (cc < 4) ? (layer ? aS2 : aS1) : (layer ? aD2 : aD1);
    unsigned short* Th = layer ? WT2h : WT1h;
    unsigned short* Tl = layer ? WT2l : WT1l;
    int h = cc & 3, base = h*32;
    float acc = 0.f;
    #pragma unroll 8
    for (int c = 0; c < 32; ++c) acc += W[k*FD + base + c] * av[base + c];
    unsigned short hh = f2bf(acc);
    Th[(128 + cc)*FD + k] = hh;
    Tl[(128 + cc)*FD + k] = f2bf(acc - bf2f(hh));
  } else if (id < 36864){
    int id2 = id - 34816;
    int layer = id2 >> 10;
    int id3 = id2 & 1023;
    int row = 136 + (id3 >> 7), k = id3 & 127;
    unsigned short* Th = layer ? WT2h : WT1h;
    unsigned short* Tl = layer ? WT2l : WT1l;
    Th[row*FD + k] = 0;
    Tl[row*FD + k] = 0;
  }
}

// ---------------- MFMA GEMM: [H(fp16, packed) | attS | attD] ----------------
template<int SPLITIN>
__global__ __launch_bounds__(256) void gemm_mfma_kernel(
    const float* __restrict__ Xf,
    const unsigned short* __restrict__ Xh, const unsigned short* __restrict__ Xl,
    const unsigned short* __restrict__ WTh, const unsigned short* __restrict__ WTl,
    uint4* __restrict__ H16, float* __restrict__ attS, float* __restrict__ attD, int n)
{
  int tid = threadIdx.x;
  int wv = tid >> 6, lane = tid & 63;
  int g = lane >> 4, r = lane & 15;
  int rbase = blockIdx.x*64 + wv*16;
  int arow = rbase + r; if (arow >= n) arow = n - 1;

  bf16x8 Ah[4], Al[4];
  if (SPLITIN){
    const bf16x8* ph = (const bf16x8*)(Xh + (size_t)arow*FD);
    const bf16x8* pl = (const bf16x8*)(Xl + (size_t)arow*FD);
    #pragma unroll
    for (int kc = 0; kc < 4; ++kc){ Ah[kc] = ph[kc*4 + g]; Al[kc] = pl[kc*4 + g]; }
  } else {
    const float4* px = (const float4*)(Xf + (size_t)arow*FD);
    #pragma unroll
    for (int kc = 0; kc < 4; ++kc){
      float4 x0 = px[(kc*4 + g)*2];
      float4 x1 = px[(kc*4 + g)*2 + 1];
      float xs[8] = {x0.x,x0.y,x0.z,x0.w,x1.x,x1.y,x1.z,x1.w};
      #pragma unroll
      for (int t = 0; t < 8; ++t){
        unsigned short hh = f2bf(xs[t]);
        Ah[kc][t] = (short)hh;
        Al[kc][t] = (short)f2bf(xs[t] - bf2f(hh));
      }
    }
  }

  f32x4 acc[9];
  #pragma unroll
  for (int ct = 0; ct < 9; ++ct) acc[ct] = (f32x4){0.f,0.f,0.f,0.f};

  #pragma unroll
  for (int ct = 0; ct < 9; ++ct){
    int wrow = ct*16 + r;
    const bf16x8* bh = (const bf16x8*)(WTh + wrow*FD);
    const bf16x8* bl = (const bf16x8*)(WTl + wrow*FD);
    #pragma unroll
    for (int kc = 0; kc < 4; ++kc){
      bf16x8 Bh = bh[kc*4 + g];
      bf16x8 Bl = bl[kc*4 + g];
      acc[ct] = __builtin_amdgcn_mfma_f32_16x16x32_bf16(Ah[kc], Bh, acc[ct], 0, 0, 0);
      acc[ct] = __builtin_amdgcn_mfma_f32_16x16x32_bf16(Ah[kc], Bl, acc[ct], 0, 0, 0);
      acc[ct] = __builtin_amdgcn_mfma_f32_16x16x32_bf16(Al[kc], Bh, acc[ct], 0, 0, 0);
    }
  }

  #pragma unroll
  for (int j = 0; j < 4; ++j){
    int row = rbase + g*4 + j;
    if (row < n){
      __half2 p0 = __float22half2_rn(make_float2(acc[0][j], acc[1][j]));
      __half2 p1 = __float22half2_rn(make_float2(acc[2][j], acc[3][j]));
      __half2 p2 = __float22half2_rn(make_float2(acc[4][j], acc[5][j]));
      __half2 p3 = __float22half2_rn(make_float2(acc[6][j], acc[7][j]));
      uint4 pk;
      pk.x = __builtin_bit_cast(unsigned, p0);
      pk.y = __builtin_bit_cast(unsigned, p1);
      pk.z = __builtin_bit_cast(unsigned, p2);
      pk.w = __builtin_bit_cast(unsigned, p3);
      H16[(size_t)row*16 + r] = pk;
      if (r < 4)      attS[row*4 + r]       = acc[8][j];
      else if (r < 8) attD[row*4 + (r - 4)] = acc[8][j];
    }
  }
}

// ---------------- per-dst softmax + aggregate (one wave per dst) ----------------
// No max-subtraction: logits are bounded (|e| < ~10, exp safe in fp32; identical
// result up to rounding). Stash stride 5 (gcd(5,32)=1 -> conflict-free LDS).
// acc[0..3] = channels 4r..4r+3 (head r<8?0:1); acc[4..7] = 64+4r..+3 (head r<8?2:3).
template<int OUT>
__global__ __launch_bounds__(256) void agg_kernel(
    const uint2* __restrict__ H16, const float* __restrict__ attS, const float* __restrict__ attD,
    const int* __restrict__ csr, const int* __restrict__ offsets,
    const float* __restrict__ bias, const float* __restrict__ wfc, const float* __restrict__ bfc,
    unsigned short* __restrict__ oh, unsigned short* __restrict__ ol,
    float* __restrict__ out, int n)
{
  __shared__ float lds[4][64*5];
  int wid = (int)((blockIdx.x * (size_t)blockDim.x + threadIdx.x) >> 6);
  int lane = threadIdx.x & 63;
  if (wid >= n) return;
  int g = lane >> 4, r = lane & 15;
  int selA = (r >> 3) & 1;
  float* wl = lds[threadIdx.x >> 6];
  int* wli = (int*)wl;

  int start = offsets[wid], end = offsets[wid+1];
  float4 ad4 = ((const float4*)attD)[wid];

  float z0=0.f, z1=0.f, z2=0.f, z3=0.f;
  float acc[8];
  #pragma unroll
  for (int k = 0; k < 8; ++k) acc[k] = 0.f;

  for (int base2 = start; base2 < end; base2 += 64){
    int cnt = end - base2; if (cnt > 64) cnt = 64;
    float p0,p1,p2,p3; int sb = 0;
    if (lane < cnt){
      int s = csr[base2 + lane];
      sb = s << 5;                    // 32 uint2 per 256B fp16 row
      float4 as4 = ((const float4*)attS)[s];
      p0 = __expf(lrelu(as4.x + ad4.x, 0.2f));
      p1 = __expf(lrelu(as4.y + ad4.y, 0.2f));
      p2 = __expf(lrelu(as4.z + ad4.z, 0.2f));
      p3 = __expf(lrelu(as4.w + ad4.w, 0.2f));
    } else { p0=p1=p2=p3=0.f; }
    z0+=p0; z1+=p1; z2+=p2; z3+=p3;
    wli[lane*5]  = sb;
    wl[lane*5+1] = p0; wl[lane*5+2] = p1; wl[lane*5+3] = p2; wl[lane*5+4] = p3;
    asm volatile("s_waitcnt lgkmcnt(0)" ::: "memory");
    __builtin_amdgcn_sched_barrier(0);
    for (int jj = g; jj < cnt; jj += 4){
      int sbj  = wli[jj*5];
      float pA = wl[jj*5 + 1 + selA];
      float pB = wl[jj*5 + 3 + selA];
      uint2 u0 = H16[(unsigned)(sbj + r)];
      uint2 u1 = H16[(unsigned)(sbj + 16 + r)];
      float2 a0 = __half22float2(__builtin_bit_cast(__half2, u0.x));
      float2 a1 = __half22float2(__builtin_bit_cast(__half2, u0.y));
      float2 a2 = __half22float2(__builtin_bit_cast(__half2, u1.x));
      float2 a3 = __half22float2(__builtin_bit_cast(__half2, u1.y));
      acc[0] += pA*a0.x; acc[1] += pA*a0.y; acc[2] += pA*a1.x; acc[3] += pA*a1.y;
      acc[4] += pB*a2.x; acc[5] += pB*a2.y; acc[6] += pB*a3.x; acc[7] += pB*a3.y;
    }
    __builtin_amdgcn_sched_barrier(0);
  }

  #pragma unroll
  for (int off = 32; off >= 1; off >>= 1){
    z0+=__shfl_xor(z0,off); z1+=__shfl_xor(z1,off);
    z2+=__shfl_xor(z2,off); z3+=__shfl_xor(z3,off);
  }
  #pragma unroll
  for (int k = 0; k < 8; ++k){
    acc[k] += __shfl_xor(acc[k], 16);
    acc[k] += __shfl_xor(acc[k], 32);
  }
  // group g keeps channels ch0 = (g>>1)*64 + 4r + 2*(g&1), ch1 = ch0+1
  float o0 = g==0?acc[0]:g==1?acc[2]:g==2?acc[4]:acc[6];
  float o1 = g==0?acc[1]:g==1?acc[3]:g==2?acc[5]:acc[7];
  int ch0 = ((g>>1)<<6) + (r<<2) + ((g&1)<<1);
  float zz = (g < 2) ? ((r<8)? z0 : z1) : ((r<8)? z2 : z3);
  float inv = 1.f / (zz + 1e-16f);
  float2 b2v = ((const float2*)bias)[ch0 >> 1];
  o0 = lrelu(o0*inv + b2v.x, 0.01f);
  o1 = lrelu(o1*inv + b2v.y, 0.01f);
  if (OUT){
    float2 w2v = ((const float2*)wfc)[ch0 >> 1];
    float t = o0*w2v.x + o1*w2v.y;
    #pragma unroll
    for (int off = 32; off >= 1; off >>= 1) t += __shfl_xor(t, off);
    if (lane == 0) out[wid] = t + bfc[0];
  } else {
    unsigned short h0 = f2bf(o0);
    unsigned short h1 = f2bf(o1);
    unsigned short l0 = f2bf(o0 - bf2f(h0));
    unsigned short l1 = f2bf(o1 - bf2f(h1));
    ((unsigned*)oh)[(size_t)wid*64 + (ch0>>1)] = (unsigned)h0 | ((unsigned)h1 << 16);
    ((unsigned*)ol)[(size_t)wid*64 + (ch0>>1)] = (unsigned)l0 | ((unsigned)l1 << 16);
  }
}

extern "C" void kernel_launch(void* const* d_in, const int* in_sizes, int n_in,
                              void* d_out, int out_size, void* d_ws, size_t ws_size,
                              hipStream_t stream)
{
  const float* x   = (const float*)d_in[0];
  const int*   ei  = (const int*)d_in[1];
  const float* W1  = (const float*)d_in[2];
  const float* aS1 = (const float*)d_in[3];
  const float* aD1 = (const float*)d_in[4];
  const float* b1  = (const float*)d_in[5];
  const float* W2  = (const float*)d_in[6];
  const float* aS2 = (const float*)d_in[7];
  const float* aD2 = (const float*)d_in[8];
  const float* b2  = (const float*)d_in[9];
  const float* Wfc = (const float*)d_in[10];
  const float* bfc = (const float*)d_in[11];
  float* out = (float*)d_out;

  int n = in_sizes[0] / FD;
  int E = in_sizes[1] / 2;
  int etot = E + n;
  unsigned rscale = (unsigned)(((8ULL << 32) + n - 1) / (unsigned long long)n);

  char* p = (char*)d_ws;
  auto alloc = [&](size_t bytes)->void*{
    void* r = (void*)p;
    p += (bytes + 255) & ~(size_t)255;
    return r;
  };
  int* counts    = (int*)alloc((size_t)n * 4);
  int* offsets   = (int*)alloc((size_t)(n + 1) * 4);
  int* csr       = (int*)alloc((size_t)etot * 4);
  float* attS1   = (float*)alloc((size_t)n * 4 * 4);
  float* attD1   = (float*)alloc((size_t)n * 4 * 4);
  float* attS2   = (float*)alloc((size_t)n * 4 * 4);
  float* attD2   = (float*)alloc((size_t)n * 4 * 4);
  unsigned short* WT1h = (unsigned short*)alloc(144*FD*2);
  unsigned short* WT1l = (unsigned short*)alloc(144*FD*2);
  unsigned short* WT2h = (unsigned short*)alloc(144*FD*2);
  unsigned short* WT2l = (unsigned short*)alloc(144*FD*2);
  uint4* H16     = (uint4*)alloc((size_t)n * FD * 2);
  unsigned short* H2h = (unsigned short*)alloc((size_t)n * FD * 2);
  unsigned short* H2l = (unsigned short*)alloc((size_t)n * FD * 2);

  hipMemsetAsync(counts, 0, (size_t)n * 4, stream);

  const int NB_PART = 512;            // 64 chunks x 8 XCD-filtered block groups
  wprep_kernel<<<144, 256, 0, stream>>>(W1, W2, aS1, aD1, aS2, aD2, WT1h, WT1l, WT2h, WT2l);
  count_part_kernel<<<NB_PART, 256, 0, stream>>>(ei + E, counts, E, rscale, NB_PART/8);
  scan_kernel<<<1, 1024, 0, stream>>>(counts, offsets, n);
  fill_part_kernel<<<NB_PART, 256, 0, stream>>>(ei, offsets, counts, csr, E, rscale, NB_PART/8);
  selfloop_kernel<<<(n + 255)/256, 256, 0, stream>>>(offsets, csr, n);

  int gb = (n + 63) / 64;
  int ab = (int)(((size_t)n * 64 + 255) / 256);

  // layer 1
  gemm_mfma_kernel<0><<<gb, 256, 0, stream>>>(x, nullptr, nullptr, WT1h, WT1l,
                                              H16, attS1, attD1, n);
  agg_kernel<0><<<ab, 256, 0, stream>>>((const uint2*)H16, attS1, attD1, csr, offsets,
                                        b1, nullptr, nullptr, H2h, H2l, nullptr, n);
  // layer 2 (+ fused FC)
  gemm_mfma_kernel<1><<<gb, 256, 0, stream>>>(nullptr, H2h, H2l, WT2h, WT2l,
                                              H16, attS2, attD2, n);
  agg_kernel<1><<<ab, 256, 0, stream>>>((const uint2*)H16, attS2, attD2, csr, offsets,
                                        b2, Wfc, bfc, nullptr, nullptr, out, n);
}